// Round 15
// baseline (163.077 us; speedup 1.0000x reference)
//
#include <hip/hip_runtime.h>
#include <math.h>

#define C_IN  256
#define HH    100
#define WW    100
#define HW    10000
#define NBAT  4
#define COUTC 256
#define K9    9
#define GG    32
#define TYN   13           // row-tiles of 8
#define TXN   9            // col-tiles of 12
#define NT2   117          // tiles per image (96 px each)
#define NWG   468          // 4*117
#define EPSF  1e-5f

typedef _Float16 f16x8 __attribute__((ext_vector_type(8)));
typedef _Float16 h2v   __attribute__((ext_vector_type(2)));
typedef float    f32x4 __attribute__((ext_vector_type(4)));

// ---------------------------------------------------------------------------
// kt_prep: one launch = x transpose (blocks 0..2511) + weight fragments
// (blocks 2512..4959).
// ---------------------------------------------------------------------------
__global__ void __launch_bounds__(256) kt_prep(const float* __restrict__ x,
                                               const float* __restrict__ wd,
                                               const float* __restrict__ w_tm,
                                               const float* __restrict__ w_tr,
                                               _Float16* __restrict__ xh,
                                               _Float16* __restrict__ wf,
                                               _Float16* __restrict__ wf6) {
  const int b = blockIdx.x;
  if (b >= 2512) {
    const int bb = b - 2512;
    if (bb < 2304) {
      const int i = bb * 256 + threadIdx.x;          // < 589824
      const int j  = i & 7;
      const int l  = (i >> 3) & 63;
      const int ot = (i >> 9) & 15;
      const int q  = i >> 13;
      const int tap = q >> 3, cg = q & 7;
      const int o = ot * 16 + (l & 15);
      const int c = cg * 32 + (l >> 4) * 8 + j;
      wf[i] = (_Float16)wd[((size_t)o * C_IN + c) * K9 + tap];
    } else {
      const int i = (bb - 2304) * 256 + threadIdx.x; // < 36864
      const int j = i & 7, l = (i >> 3) & 63, q = i >> 9;
      const int tap = q >> 3, cg = q & 7;
      const int o = l & 15;
      const int c = cg * 32 + (l >> 4) * 8 + j;
      float v = 0.f;
      if (o < 4)      v = w_tm[((size_t)o * C_IN + c) * K9 + tap];
      else if (o < 6) v = w_tr[((size_t)(o - 4) * C_IN + c) * K9 + tap];
      wf6[i] = (_Float16)v;
    }
    return;
  }
  // --- transpose part ---
  __shared__ float T[64][65];
  const int n = b / (4 * 157);
  const int r = b % (4 * 157);
  const int cg = r / 157, tile = r % 157;
  const int pbase = tile * 64, c0 = cg * 64;
  const int tid = threadIdx.x, lane = tid & 63, wv = tid >> 6;

#pragma unroll 4
  for (int i = 0; i < 16; ++i) {
    const int c = c0 + wv * 16 + i;
    const int pix = pbase + lane;
    T[wv * 16 + i][lane] = (pix < HW) ? x[((size_t)n * C_IN + c) * HW + pix] : 0.f;
  }
  __syncthreads();

  const int cl = tid & 15;
#pragma unroll
  for (int j = 0; j < 4; ++j) {
    const int pxl = (tid >> 4) + j * 16;
    const int pix = pbase + pxl;
    if (pix < HW) {
      const float v0 = T[cl * 4 + 0][pxl], v1 = T[cl * 4 + 1][pxl];
      const float v2 = T[cl * 4 + 2][pxl], v3 = T[cl * 4 + 3][pxl];
      uint2 pk;
      h2v a = {(_Float16)v0, (_Float16)v1};
      h2v bq = {(_Float16)v2, (_Float16)v3};
      pk.x = __builtin_bit_cast(unsigned, a);
      pk.y = __builtin_bit_cast(unsigned, bq);
      *(uint2*)(xh + ((size_t)n * HW + pix) * C_IN + c0 + cl * 4) = pk;
    }
  }
}

#define RAW_BARRIER()                                                         \
  asm volatile("s_waitcnt lgkmcnt(0)" ::: "memory");                          \
  __builtin_amdgcn_sched_barrier(0);                                          \
  __builtin_amdgcn_s_barrier();                                               \
  __builtin_amdgcn_sched_barrier(0);

// ---------------------------------------------------------------------------
// k1: offset conv, wave-independent; XCD-chunked block swizzle.
// ---------------------------------------------------------------------------
__global__ void __launch_bounds__(256) k1_off(
    const _Float16* __restrict__ xh, const _Float16* __restrict__ wf6,
    const float* __restrict__ b_tm, const float* __restrict__ b_tr,
    float* __restrict__ posy, float* __restrict__ posx) {
  const int ob = blockIdx.x;
  const int xcd = ob & 7, loc = ob >> 3;
  const int sblk = (xcd < 1 ? xcd * 79 : 79 + (xcd - 1) * 78) + loc;
  const int tid = threadIdx.x, lane = tid & 63, wv = tid >> 6;
  const int s = sblk * 4 + wv;              // 0..2499
  const int n = s / 625, strip = s % 625;
  const int ps = strip * 16;
  const int px = ps + (lane & 15);
  const int h = px / WW, w = px % WW;
  const char* xbase = (const char*)(xh + (size_t)n * HW * C_IN) + (lane >> 4) * 16;

  int nbA, nbB; bool vA, vB;
#define K1NB(T_, NB, V)                                                       \
  { const int y = h + (T_) / 3 - 1, xx = w + (T_) % 3 - 1;                    \
    V = ((unsigned)y < (unsigned)HH) && ((unsigned)xx < (unsigned)WW);        \
    NB = (V ? (y * WW + xx) : 0) * 512; }

  uint4 q0, q1, q2, q3;
  K1NB(0, nbA, vA)
  nbB = nbA; vB = vA;
  q0 = *(const uint4*)(xbase + nbA + 0 * 64);
  q1 = *(const uint4*)(xbase + nbA + 1 * 64);
  q2 = *(const uint4*)(xbase + nbA + 2 * 64);
  q3 = *(const uint4*)(xbase + nbA + 3 * 64);
  f16x8 afA = *(const f16x8*)(wf6 + (size_t)0 * 512 + lane * 8);
  f16x8 afB = *(const f16x8*)(wf6 + (size_t)1 * 512 + lane * 8);

  f32x4 acc = (f32x4)(0.f);
  const uint4 z4 = {0u, 0u, 0u, 0u};

#define K1SUB(CG, Q, AF)                                                      \
  {                                                                           \
    const int p = t * 8 + (CG);                                               \
    uint4 bq = vA ? Q : z4;                                                   \
    f16x8 bf = __builtin_bit_cast(f16x8, bq);                                 \
    if ((CG) == 2) { K1NB((t < 8 ? t + 1 : 8), nbB, vB) }                     \
    if ((CG) < 4) { Q = *(const uint4*)(xbase + nbA + ((CG) + 4) * 64); }     \
    else if (t < 8) { Q = *(const uint4*)(xbase + nbB + ((CG) - 4) * 64); }   \
    acc = __builtin_amdgcn_mfma_f32_16x16x32_f16(AF, bf, acc, 0, 0, 0);       \
    if ((CG) < 6 || t < 8)                                                    \
      AF = *(const f16x8*)(wf6 + (size_t)(p + 2) * 512 + lane * 8);           \
  }

  for (int t = 0; t < 9; ++t) {
    K1SUB(0, q0, afA) K1SUB(1, q1, afB) K1SUB(2, q2, afA) K1SUB(3, q3, afB)
    K1SUB(4, q0, afA) K1SUB(5, q1, afB) K1SUB(6, q2, afA) K1SUB(7, q3, afB)
    nbA = nbB; vA = vB;
  }

  const float t0v = __shfl(acc[0], (lane & 15) + 16);
  const float t1v = __shfl(acc[1], (lane & 15) + 16);
  if (lane < 16) {
    const float A00 = acc[0] + b_tm[0], A01 = acc[1] + b_tm[1];
    const float A10 = acc[2] + b_tm[2], A11 = acc[3] + b_tm[3];
    const float t0 = t0v + b_tr[0], t1 = t1v + b_tr[1];
    const float fh = (float)h, fw = (float)w;
#pragma unroll
    for (int k = 0; k < 9; ++k) {
      const float ry = (float)(k / 3 - 1);
      const float rx = (float)(k % 3 - 1);
      posy[((size_t)n * K9 + k) * HW + px] = fh + t0 + A00 * ry + A01 * rx;
      posx[((size_t)n * K9 + k) * HW + px] = fw + t1 + A10 * ry + A11 * rx;
    }
  }
}

// ---------------------------------------------------------------------------
// k2: deformable conv fp16 MFMA GEMM — R12/R14 body (75 us measured) with
// ONE isolated change: nontemporal C-stores (keep dead output from evicting
// xh/wfrag in L2). Everything else byte-identical.
// ---------------------------------------------------------------------------
__global__ void __launch_bounds__(512, 4) k2_deform(
    const _Float16* __restrict__ xh, const _Float16* __restrict__ wfrag,
    const float* __restrict__ posy, const float* __restrict__ posx,
    float* __restrict__ out, float* __restrict__ part) {
  __shared__ __align__(16) char Bs[2 * 96 * 64];        // 12 KB
  __shared__ __align__(16) unsigned int ctab[864 * 8];  // 27.65 KB (gr alias later)

  // bijective XCD-chunk map: nwg=468, q=58, r=4
  const int ob = blockIdx.x;
  const int xcd = ob & 7, loc = ob >> 3;
  const int wg = (xcd < 4 ? xcd * 59 : 236 + (xcd - 4) * 58) + loc;
  const int n = wg / NT2, rem = wg % NT2;
  const int ty = rem / TXN, tx = rem % TXN;

  const int tid = threadIdx.x, lane = tid & 63, wv = tid >> 6;
  const bool stg = tid < 384;                    // staging: 96 px x 4 quads
  const int px_s = tid >> 2, qo = tid & 3;
  const int wsw = (((qo + (px_s >> 1)) & 3) << 4);
  const int rpx = lane & 15, rko = lane >> 4;
  const int rsw = (((rko + (rpx >> 1)) & 3) << 4);

  // --- corner tables: 864 = 9 taps x 96 px ---
  for (int s = tid; s < 864; s += 512) {
    const int tap = s / 96, j = s % 96;
    const int row = ty * 8 + j / 12, col = tx * 12 + j % 12;
    const bool pvv = (row < HH) && (col < WW);
    const int mpa = pvv ? (row * WW + col) : 0;
    float ys = posy[((size_t)n * K9 + tap) * HW + mpa];
    float xs = posx[((size_t)n * K9 + tap) * HW + mpa];
    if (!pvv) { ys = -1e4f; xs = -1e4f; }
    const float y0f = floorf(ys), x0f = floorf(xs);
    const float wy = ys - y0f, wx = xs - x0f;
    const int iy0 = (int)y0f, ix0 = (int)x0f;
    const bool vy0 = ((unsigned)iy0 < (unsigned)HH);
    const bool vy1 = ((unsigned)(iy0 + 1) < (unsigned)HH);
    const bool vx0 = ((unsigned)ix0 < (unsigned)WW);
    const bool vx1 = ((unsigned)(ix0 + 1) < (unsigned)WW);
    const bool v0 = vy0 && vx0, v1 = vy0 && vx1;
    const bool v2 = vy1 && vx0, v3 = vy1 && vx1;
    uint4 oa, wa;
    oa.x = (v0 ? (iy0 * WW + ix0) : 0) * 512u;
    oa.y = (v1 ? (iy0 * WW + ix0 + 1) : 0) * 512u;
    oa.z = (v2 ? ((iy0 + 1) * WW + ix0) : 0) * 512u;
    oa.w = (v3 ? ((iy0 + 1) * WW + ix0 + 1) : 0) * 512u;
    const float g0 = v0 ? (1.f - wy) * (1.f - wx) : 0.f;
    const float g1 = v1 ? (1.f - wy) * wx : 0.f;
    const float g2 = v2 ? wy * (1.f - wx) : 0.f;
    const float g3 = v3 ? wy * wx : 0.f;
    const _Float16 h0 = (_Float16)g0, h1 = (_Float16)g1;
    const _Float16 h2_ = (_Float16)g2, h3 = (_Float16)g3;
    wa.x = __builtin_bit_cast(unsigned, (h2v){h0, h0});
    wa.y = __builtin_bit_cast(unsigned, (h2v){h1, h1});
    wa.z = __builtin_bit_cast(unsigned, (h2v){h2_, h2_});
    wa.w = __builtin_bit_cast(unsigned, (h2v){h3, h3});
    uint4* cp = (uint4*)&ctab[s * 8];
    cp[0] = oa;
    cp[1] = wa;
  }
  __syncthreads();

  const char* xbase = (const char*)(xh + (size_t)n * HW * C_IN);

  uint4 O, Wt, c0, c1, c2, c3;
  f16x8 aA0, aA1, aB0, aB1;

  // section S: tap = S>>3, cg = S&7 (32 channels).
#define ISSUE(S)                                                              \
  if (stg) {                                                                  \
    const uint4* ce = (const uint4*)&ctab[(((S) >> 3) * 96 + px_s) * 8];      \
    O = ce[0];                                                                \
    Wt = ce[1];                                                               \
    const int choff = ((S) & 7) * 64 + qo * 16;                               \
    c0 = *(const uint4*)(xbase + O.x + choff);                                \
    c1 = *(const uint4*)(xbase + O.y + choff);                                \
    c2 = *(const uint4*)(xbase + O.z + choff);                                \
    c3 = *(const uint4*)(xbase + O.w + choff);                                \
  }

#define CW1(c)                                                                \
  __builtin_bit_cast(unsigned,                                                \
      (h2v)(w0 * __builtin_bit_cast(h2v, c0.c) +                              \
            w1 * __builtin_bit_cast(h2v, c1.c) +                              \
            w2 * __builtin_bit_cast(h2v, c2.c) +                              \
            w3 * __builtin_bit_cast(h2v, c3.c)))

#define COMBINE_WRITE(BUFW)                                                   \
  if (stg) {                                                                  \
    h2v w0 = __builtin_bit_cast(h2v, Wt.x), w1 = __builtin_bit_cast(h2v, Wt.y); \
    h2v w2 = __builtin_bit_cast(h2v, Wt.z), w3 = __builtin_bit_cast(h2v, Wt.w); \
    uint4 sv;                                                                 \
    sv.x = CW1(x);                                                            \
    sv.y = CW1(y);                                                            \
    sv.z = CW1(z);                                                            \
    sv.w = CW1(w);                                                            \
    *(uint4*)(Bs + (BUFW) * 6144 + px_s * 64 + wsw) = sv;                     \
  }

#define LOADA(A0_, A1_, CK)                                                   \
  {                                                                           \
    const _Float16* wfp = wfrag + (((size_t)(CK) * 16 + wv * 2) * 64 + lane) * 8; \
    A0_ = *(const f16x8*)(wfp);                                               \
    A1_ = *(const f16x8*)(wfp + 512);                                         \
  }

  f32x4 acc[2][6];
#pragma unroll
  for (int ot = 0; ot < 2; ++ot)
#pragma unroll
    for (int bt = 0; bt < 6; ++bt) acc[ot][bt] = (f32x4)(0.f);

#define MF(a, bx, o_, b_) \
  acc[o_][b_] = __builtin_amdgcn_mfma_f32_16x16x32_f16(a, bx, acc[o_][b_], 0, 0, 0);

#define MFMA12(A0_, A1_, BUF)                                                 \
  {                                                                           \
    const char* bb = Bs + (BUF) * 6144 + rpx * 64 + rsw;                      \
    f16x8 b0 = *(const f16x8*)(bb);                                           \
    f16x8 b1 = *(const f16x8*)(bb + 1024);                                    \
    f16x8 b2 = *(const f16x8*)(bb + 2048);                                    \
    f16x8 b3 = *(const f16x8*)(bb + 3072);                                    \
    f16x8 b4 = *(const f16x8*)(bb + 4096);                                    \
    f16x8 b5 = *(const f16x8*)(bb + 5120);                                    \
    __builtin_amdgcn_s_setprio(1);                                            \
    MF(A0_, b0, 0, 0) MF(A1_, b0, 1, 0)                                       \
    MF(A0_, b1, 0, 1) MF(A1_, b1, 1, 1)                                       \
    MF(A0_, b2, 0, 2) MF(A1_, b2, 1, 2)                                       \
    MF(A0_, b3, 0, 3) MF(A1_, b3, 1, 3)                                       \
    MF(A0_, b4, 0, 4) MF(A1_, b4, 1, 4)                                       \
    MF(A0_, b5, 0, 5) MF(A1_, b5, 1, 5)                                       \
    __builtin_amdgcn_s_setprio(0);                                            \
  }

  // --- prologue ---
  ISSUE(0)
  COMBINE_WRITE(0)
  ISSUE(1)
  LOADA(aA0, aA1, 0)
  LOADA(aB0, aB1, 1)
  RAW_BARRIER()

  // --- sections 0..69 (35 x 2) ---
  for (int sp = 0; sp < 35; ++sp) {
    const int s0 = 2 * sp, s1 = 2 * sp + 1;
    MFMA12(aA0, aA1, 0)
    LOADA(aA0, aA1, s0 + 2)
    COMBINE_WRITE(1)
    ISSUE(s0 + 2)
    RAW_BARRIER()
    MFMA12(aB0, aB1, 1)
    LOADA(aB0, aB1, s1 + 2)
    COMBINE_WRITE(0)
    ISSUE(s1 + 2)
    RAW_BARRIER()
  }
  // section 70 (buf0): stage 71 into buf1
  MFMA12(aA0, aA1, 0)
  COMBINE_WRITE(1)
  RAW_BARRIER()
  // section 71 (buf1)
  MFMA12(aB0, aB1, 1)

  // --- epilogue: nontemporal stores + GN partials (gr aliased onto ctab) ---
  float* grA = (float*)ctab;          // [16][64]
  float* grB = grA + 1024;
  const int colb = lane & 15, prow = (lane >> 4) * 4;
#pragma unroll
  for (int ot = 0; ot < 2; ++ot) {
    float s1 = 0.f, s2 = 0.f;
#pragma unroll
    for (int bt = 0; bt < 6; ++bt) {
      const int jj = bt * 16 + colb;
      const int row = ty * 8 + jj / 12, col = tx * 12 + jj % 12;
      const f32x4 a = acc[ot][bt];
      if (row < HH && col < WW) {
        float* op = out + ((size_t)(n * COUTC + wv * 32 + ot * 16 + prow)) * HW +
                    row * WW + col;
        __builtin_nontemporal_store(a[0], op);
        __builtin_nontemporal_store(a[1], op + HW);
        __builtin_nontemporal_store(a[2], op + 2 * HW);
        __builtin_nontemporal_store(a[3], op + 3 * HW);
      }
      s1 += a[0] + a[1] + a[2] + a[3];
      s2 += a[0] * a[0] + a[1] * a[1] + a[2] * a[2] + a[3] * a[3];
    }
    grA[(wv * 2 + ot) * 64 + lane] = s1;
    grB[(wv * 2 + ot) * 64 + lane] = s2;
  }
  __syncthreads();
  if (tid < 32) {
    const int wv2 = tid >> 2, ot2 = (tid >> 1) & 1, hb = tid & 1;
    float a1 = 0.f, a2 = 0.f;
#pragma unroll 8
    for (int l = 0; l < 32; ++l) {
      a1 += grA[(wv2 * 2 + ot2) * 64 + hb * 32 + l];
      a2 += grB[(wv2 * 2 + ot2) * 64 + hb * 32 + l];
    }
    float* pp = part + (((size_t)n * NT2 + rem) * GG + tid) * 2;
    pp[0] = a1;
    pp[1] = a2;
  }
}

// ---------------------------------------------------------------------------
// k4: GroupNorm affine + ReLU, stats fused. 4096 elems/block (grid 2500):
// 4x fewer redundant partial-reductions than the 10000-block version.
// A block spans <=2 groups (4096 < HW so at most one channel boundary).
// ---------------------------------------------------------------------------
__global__ void __launch_bounds__(256) k4_norm(float* __restrict__ out,
                                               const float* __restrict__ part,
                                               const float* __restrict__ gw,
                                               const float* __restrict__ gb) {
  const int b = blockIdx.x;              // 2500
  const int tid = threadIdx.x;
  const size_t idx0 = (size_t)b * 4096;
  const int n = (int)(idx0 / ((size_t)COUTC * HW));
  const int r0 = (int)(idx0 % ((size_t)COUTC * HW));
  const int gfirst = (r0 / HW) >> 3;
  const int glast = ((r0 + 4095) / HW) >> 3;
  const int ngrp = (glast > gfirst) ? 2 : 1;

  __shared__ float rr[4][2];
  __shared__ float sm[2][2];

  for (int wgrp = 0; wgrp < ngrp; ++wgrp) {
    const int g = wgrp ? glast : gfirst;
    float s1 = 0.f, s2 = 0.f;
    if (tid < NT2) {
      const float* pp = part + (((size_t)n * NT2 + tid) * GG + g) * 2;
      s1 = pp[0];
      s2 = pp[1];
    }
#pragma unroll
    for (int off = 32; off > 0; off >>= 1) {
      s1 += __shfl_down(s1, off);
      s2 += __shfl_down(s2, off);
    }
    if ((tid & 63) == 0) { rr[tid >> 6][0] = s1; rr[tid >> 6][1] = s2; }
    __syncthreads();
    if (tid == 0) {
      const float a1 = rr[0][0] + rr[1][0] + rr[2][0] + rr[3][0];
      const float a2 = rr[0][1] + rr[1][1] + rr[2][1] + rr[3][1];
      const float cnt = 8.0f * (float)HW;
      const float mean = a1 / cnt;
      const float var = a2 / cnt - mean * mean;
      sm[wgrp][0] = mean;
      sm[wgrp][1] = rsqrtf(var + EPSF);
    }
    __syncthreads();
  }

#pragma unroll
  for (int p = 0; p < 4; ++p) {
    const size_t idx = idx0 + (size_t)p * 1024 + (size_t)tid * 4;
    const int o = (int)((idx % ((size_t)COUTC * HW)) / HW);
    const int g = o >> 3;
    const int which = (g == gfirst) ? 0 : 1;
    const float mean = sm[which][0];
    const float rs = sm[which][1];
    const float sc = rs * gw[o];
    const float sh = gb[o] - mean * sc;
    float4 v = *(float4*)(out + idx);
    v.x = fmaxf(fmaf(v.x, sc, sh), 0.f);
    v.y = fmaxf(fmaf(v.y, sc, sh), 0.f);
    v.z = fmaxf(fmaf(v.z, sc, sh), 0.f);
    v.w = fmaxf(fmaf(v.w, sc, sh), 0.f);
    *(float4*)(out + idx) = v;
  }
}

// ---------------------------------------------------------------------------
extern "C" void kernel_launch(void* const* d_in, const int* in_sizes, int n_in,
                              void* d_out, int out_size, void* d_ws, size_t ws_size,
                              hipStream_t stream) {
  const float* x    = (const float*)d_in[0];
  const float* w_tm = (const float*)d_in[1];
  const float* b_tm = (const float*)d_in[2];
  const float* w_tr = (const float*)d_in[3];
  const float* b_tr = (const float*)d_in[4];
  const float* w_def = (const float*)d_in[5];
  const float* gn_w = (const float*)d_in[6];
  const float* gn_b = (const float*)d_in[7];
  float* out = (float*)d_out;
  float* ws = (float*)d_ws;

  float* posy  = ws;                                     // 360000 f32
  float* posx  = ws + 360000;                            // 360000 f32
  _Float16* wfrag = (_Float16*)(ws + 720000);            // 589824 fp16
  _Float16* wf6   = (_Float16*)(ws + 1014912);           // 36864 fp16
  _Float16* xh    = (_Float16*)(ws + 1033344);           // 10.24M fp16
  float* part  = ws + 6153344;                           // 4*117*32*2 = 29952 f32

  hipLaunchKernelGGL(kt_prep, dim3(4960), dim3(256), 0, stream,
                     x, w_def, w_tm, w_tr, xh, wfrag, wf6);
  hipLaunchKernelGGL(k1_off, dim3(625), dim3(256), 0, stream,
                     xh, wf6, b_tm, b_tr, posy, posx);
  hipLaunchKernelGGL(k2_deform, dim3(NWG), dim3(512), 0, stream,
                     xh, wfrag, posy, posx, out, part);
  hipLaunchKernelGGL(k4_norm, dim3(2500), dim3(256), 0, stream,
                     out, part, gn_w, gn_b);
}

// Round 16
// 131.300 us; speedup vs baseline: 1.2420x; 1.2420x over previous
//
#include <hip/hip_runtime.h>
#include <math.h>

#define C_IN  256
#define HH    100
#define WW    100
#define HW    10000
#define NBAT  4
#define COUTC 256
#define K9    9
#define GG    32
#define TYN   13           // row-tiles of 8
#define TXN   9            // col-tiles of 12
#define NT2   117          // tiles per image (96 px each)
#define NWG   468          // 4*117
#define EPSF  1e-5f

typedef _Float16 f16x8 __attribute__((ext_vector_type(8)));
typedef _Float16 h2v   __attribute__((ext_vector_type(2)));
typedef float    f32x4 __attribute__((ext_vector_type(4)));

// ---------------------------------------------------------------------------
// kt_prep: one launch = x transpose (blocks 0..2511) + weight fragments
// (blocks 2512..4959).
// ---------------------------------------------------------------------------
__global__ void __launch_bounds__(256) kt_prep(const float* __restrict__ x,
                                               const float* __restrict__ wd,
                                               const float* __restrict__ w_tm,
                                               const float* __restrict__ w_tr,
                                               _Float16* __restrict__ xh,
                                               _Float16* __restrict__ wf,
                                               _Float16* __restrict__ wf6) {
  const int b = blockIdx.x;
  if (b >= 2512) {
    const int bb = b - 2512;
    if (bb < 2304) {
      const int i = bb * 256 + threadIdx.x;          // < 589824
      const int j  = i & 7;
      const int l  = (i >> 3) & 63;
      const int ot = (i >> 9) & 15;
      const int q  = i >> 13;
      const int tap = q >> 3, cg = q & 7;
      const int o = ot * 16 + (l & 15);
      const int c = cg * 32 + (l >> 4) * 8 + j;
      wf[i] = (_Float16)wd[((size_t)o * C_IN + c) * K9 + tap];
    } else {
      const int i = (bb - 2304) * 256 + threadIdx.x; // < 36864
      const int j = i & 7, l = (i >> 3) & 63, q = i >> 9;
      const int tap = q >> 3, cg = q & 7;
      const int o = l & 15;
      const int c = cg * 32 + (l >> 4) * 8 + j;
      float v = 0.f;
      if (o < 4)      v = w_tm[((size_t)o * C_IN + c) * K9 + tap];
      else if (o < 6) v = w_tr[((size_t)(o - 4) * C_IN + c) * K9 + tap];
      wf6[i] = (_Float16)v;
    }
    return;
  }
  // --- transpose part ---
  __shared__ float T[64][65];
  const int n = b / (4 * 157);
  const int r = b % (4 * 157);
  const int cg = r / 157, tile = r % 157;
  const int pbase = tile * 64, c0 = cg * 64;
  const int tid = threadIdx.x, lane = tid & 63, wv = tid >> 6;

#pragma unroll 4
  for (int i = 0; i < 16; ++i) {
    const int c = c0 + wv * 16 + i;
    const int pix = pbase + lane;
    T[wv * 16 + i][lane] = (pix < HW) ? x[((size_t)n * C_IN + c) * HW + pix] : 0.f;
  }
  __syncthreads();

  const int cl = tid & 15;
#pragma unroll
  for (int j = 0; j < 4; ++j) {
    const int pxl = (tid >> 4) + j * 16;
    const int pix = pbase + pxl;
    if (pix < HW) {
      const float v0 = T[cl * 4 + 0][pxl], v1 = T[cl * 4 + 1][pxl];
      const float v2 = T[cl * 4 + 2][pxl], v3 = T[cl * 4 + 3][pxl];
      uint2 pk;
      h2v a = {(_Float16)v0, (_Float16)v1};
      h2v bq = {(_Float16)v2, (_Float16)v3};
      pk.x = __builtin_bit_cast(unsigned, a);
      pk.y = __builtin_bit_cast(unsigned, bq);
      *(uint2*)(xh + ((size_t)n * HW + pix) * C_IN + c0 + cl * 4) = pk;
    }
  }
}

#define RAW_BARRIER()                                                         \
  asm volatile("s_waitcnt lgkmcnt(0)" ::: "memory");                          \
  __builtin_amdgcn_sched_barrier(0);                                          \
  __builtin_amdgcn_s_barrier();                                               \
  __builtin_amdgcn_sched_barrier(0);

// ---------------------------------------------------------------------------
// k1: offset conv, wave-independent; XCD-chunked block swizzle.
// ---------------------------------------------------------------------------
__global__ void __launch_bounds__(256) k1_off(
    const _Float16* __restrict__ xh, const _Float16* __restrict__ wf6,
    const float* __restrict__ b_tm, const float* __restrict__ b_tr,
    float* __restrict__ posy, float* __restrict__ posx) {
  const int ob = blockIdx.x;
  const int xcd = ob & 7, loc = ob >> 3;
  const int sblk = (xcd < 1 ? xcd * 79 : 79 + (xcd - 1) * 78) + loc;
  const int tid = threadIdx.x, lane = tid & 63, wv = tid >> 6;
  const int s = sblk * 4 + wv;              // 0..2499
  const int n = s / 625, strip = s % 625;
  const int ps = strip * 16;
  const int px = ps + (lane & 15);
  const int h = px / WW, w = px % WW;
  const char* xbase = (const char*)(xh + (size_t)n * HW * C_IN) + (lane >> 4) * 16;

  int nbA, nbB; bool vA, vB;
#define K1NB(T_, NB, V)                                                       \
  { const int y = h + (T_) / 3 - 1, xx = w + (T_) % 3 - 1;                    \
    V = ((unsigned)y < (unsigned)HH) && ((unsigned)xx < (unsigned)WW);        \
    NB = (V ? (y * WW + xx) : 0) * 512; }

  uint4 q0, q1, q2, q3;
  K1NB(0, nbA, vA)
  nbB = nbA; vB = vA;
  q0 = *(const uint4*)(xbase + nbA + 0 * 64);
  q1 = *(const uint4*)(xbase + nbA + 1 * 64);
  q2 = *(const uint4*)(xbase + nbA + 2 * 64);
  q3 = *(const uint4*)(xbase + nbA + 3 * 64);
  f16x8 afA = *(const f16x8*)(wf6 + (size_t)0 * 512 + lane * 8);
  f16x8 afB = *(const f16x8*)(wf6 + (size_t)1 * 512 + lane * 8);

  f32x4 acc = (f32x4)(0.f);
  const uint4 z4 = {0u, 0u, 0u, 0u};

#define K1SUB(CG, Q, AF)                                                      \
  {                                                                           \
    const int p = t * 8 + (CG);                                               \
    uint4 bq = vA ? Q : z4;                                                   \
    f16x8 bf = __builtin_bit_cast(f16x8, bq);                                 \
    if ((CG) == 2) { K1NB((t < 8 ? t + 1 : 8), nbB, vB) }                     \
    if ((CG) < 4) { Q = *(const uint4*)(xbase + nbA + ((CG) + 4) * 64); }     \
    else if (t < 8) { Q = *(const uint4*)(xbase + nbB + ((CG) - 4) * 64); }   \
    acc = __builtin_amdgcn_mfma_f32_16x16x32_f16(AF, bf, acc, 0, 0, 0);       \
    if ((CG) < 6 || t < 8)                                                    \
      AF = *(const f16x8*)(wf6 + (size_t)(p + 2) * 512 + lane * 8);           \
  }

  for (int t = 0; t < 9; ++t) {
    K1SUB(0, q0, afA) K1SUB(1, q1, afB) K1SUB(2, q2, afA) K1SUB(3, q3, afB)
    K1SUB(4, q0, afA) K1SUB(5, q1, afB) K1SUB(6, q2, afA) K1SUB(7, q3, afB)
    nbA = nbB; vA = vB;
  }

  const float t0v = __shfl(acc[0], (lane & 15) + 16);
  const float t1v = __shfl(acc[1], (lane & 15) + 16);
  if (lane < 16) {
    const float A00 = acc[0] + b_tm[0], A01 = acc[1] + b_tm[1];
    const float A10 = acc[2] + b_tm[2], A11 = acc[3] + b_tm[3];
    const float t0 = t0v + b_tr[0], t1 = t1v + b_tr[1];
    const float fh = (float)h, fw = (float)w;
#pragma unroll
    for (int k = 0; k < 9; ++k) {
      const float ry = (float)(k / 3 - 1);
      const float rx = (float)(k % 3 - 1);
      posy[((size_t)n * K9 + k) * HW + px] = fh + t0 + A00 * ry + A01 * rx;
      posx[((size_t)n * K9 + k) * HW + px] = fw + t1 + A10 * ry + A11 * rx;
    }
  }
}

// ---------------------------------------------------------------------------
// k2: deformable conv fp16 MFMA GEMM — exact R12/R14 body (75 us measured).
// R15's nontemporal stores REGRESSED (+37 us: nt bypasses L2 write-combining;
// scattered 16B column-stores became HBM partial-line bursts) — reverted to
// regular stores. This kernel is at ~85% of the scattered-access L2 BW
// ceiling (~29 of 34.5 TB/s): corner gathers are inherently 64B-granular.
// ---------------------------------------------------------------------------
__global__ void __launch_bounds__(512, 4) k2_deform(
    const _Float16* __restrict__ xh, const _Float16* __restrict__ wfrag,
    const float* __restrict__ posy, const float* __restrict__ posx,
    float* __restrict__ out, float* __restrict__ part) {
  __shared__ __align__(16) char Bs[2 * 96 * 64];        // 12 KB
  __shared__ __align__(16) unsigned int ctab[864 * 8];  // 27.65 KB (gr alias later)

  // bijective XCD-chunk map: nwg=468, q=58, r=4
  const int ob = blockIdx.x;
  const int xcd = ob & 7, loc = ob >> 3;
  const int wg = (xcd < 4 ? xcd * 59 : 236 + (xcd - 4) * 58) + loc;
  const int n = wg / NT2, rem = wg % NT2;
  const int ty = rem / TXN, tx = rem % TXN;

  const int tid = threadIdx.x, lane = tid & 63, wv = tid >> 6;
  const bool stg = tid < 384;                    // staging: 96 px x 4 quads
  const int px_s = tid >> 2, qo = tid & 3;
  const int wsw = (((qo + (px_s >> 1)) & 3) << 4);
  const int rpx = lane & 15, rko = lane >> 4;
  const int rsw = (((rko + (rpx >> 1)) & 3) << 4);

  // --- corner tables: 864 = 9 taps x 96 px ---
  for (int s = tid; s < 864; s += 512) {
    const int tap = s / 96, j = s % 96;
    const int row = ty * 8 + j / 12, col = tx * 12 + j % 12;
    const bool pvv = (row < HH) && (col < WW);
    const int mpa = pvv ? (row * WW + col) : 0;
    float ys = posy[((size_t)n * K9 + tap) * HW + mpa];
    float xs = posx[((size_t)n * K9 + tap) * HW + mpa];
    if (!pvv) { ys = -1e4f; xs = -1e4f; }
    const float y0f = floorf(ys), x0f = floorf(xs);
    const float wy = ys - y0f, wx = xs - x0f;
    const int iy0 = (int)y0f, ix0 = (int)x0f;
    const bool vy0 = ((unsigned)iy0 < (unsigned)HH);
    const bool vy1 = ((unsigned)(iy0 + 1) < (unsigned)HH);
    const bool vx0 = ((unsigned)ix0 < (unsigned)WW);
    const bool vx1 = ((unsigned)(ix0 + 1) < (unsigned)WW);
    const bool v0 = vy0 && vx0, v1 = vy0 && vx1;
    const bool v2 = vy1 && vx0, v3 = vy1 && vx1;
    uint4 oa, wa;
    oa.x = (v0 ? (iy0 * WW + ix0) : 0) * 512u;
    oa.y = (v1 ? (iy0 * WW + ix0 + 1) : 0) * 512u;
    oa.z = (v2 ? ((iy0 + 1) * WW + ix0) : 0) * 512u;
    oa.w = (v3 ? ((iy0 + 1) * WW + ix0 + 1) : 0) * 512u;
    const float g0 = v0 ? (1.f - wy) * (1.f - wx) : 0.f;
    const float g1 = v1 ? (1.f - wy) * wx : 0.f;
    const float g2 = v2 ? wy * (1.f - wx) : 0.f;
    const float g3 = v3 ? wy * wx : 0.f;
    const _Float16 h0 = (_Float16)g0, h1 = (_Float16)g1;
    const _Float16 h2_ = (_Float16)g2, h3 = (_Float16)g3;
    wa.x = __builtin_bit_cast(unsigned, (h2v){h0, h0});
    wa.y = __builtin_bit_cast(unsigned, (h2v){h1, h1});
    wa.z = __builtin_bit_cast(unsigned, (h2v){h2_, h2_});
    wa.w = __builtin_bit_cast(unsigned, (h2v){h3, h3});
    uint4* cp = (uint4*)&ctab[s * 8];
    cp[0] = oa;
    cp[1] = wa;
  }
  __syncthreads();

  const char* xbase = (const char*)(xh + (size_t)n * HW * C_IN);

  uint4 O, Wt, c0, c1, c2, c3;
  f16x8 aA0, aA1, aB0, aB1;

  // section S: tap = S>>3, cg = S&7 (32 channels).
#define ISSUE(S)                                                              \
  if (stg) {                                                                  \
    const uint4* ce = (const uint4*)&ctab[(((S) >> 3) * 96 + px_s) * 8];      \
    O = ce[0];                                                                \
    Wt = ce[1];                                                               \
    const int choff = ((S) & 7) * 64 + qo * 16;                               \
    c0 = *(const uint4*)(xbase + O.x + choff);                                \
    c1 = *(const uint4*)(xbase + O.y + choff);                                \
    c2 = *(const uint4*)(xbase + O.z + choff);                                \
    c3 = *(const uint4*)(xbase + O.w + choff);                                \
  }

#define CW1(c)                                                                \
  __builtin_bit_cast(unsigned,                                                \
      (h2v)(w0 * __builtin_bit_cast(h2v, c0.c) +                              \
            w1 * __builtin_bit_cast(h2v, c1.c) +                              \
            w2 * __builtin_bit_cast(h2v, c2.c) +                              \
            w3 * __builtin_bit_cast(h2v, c3.c)))

#define COMBINE_WRITE(BUFW)                                                   \
  if (stg) {                                                                  \
    h2v w0 = __builtin_bit_cast(h2v, Wt.x), w1 = __builtin_bit_cast(h2v, Wt.y); \
    h2v w2 = __builtin_bit_cast(h2v, Wt.z), w3 = __builtin_bit_cast(h2v, Wt.w); \
    uint4 sv;                                                                 \
    sv.x = CW1(x);                                                            \
    sv.y = CW1(y);                                                            \
    sv.z = CW1(z);                                                            \
    sv.w = CW1(w);                                                            \
    *(uint4*)(Bs + (BUFW) * 6144 + px_s * 64 + wsw) = sv;                     \
  }

#define LOADA(A0_, A1_, CK)                                                   \
  {                                                                           \
    const _Float16* wfp = wfrag + (((size_t)(CK) * 16 + wv * 2) * 64 + lane) * 8; \
    A0_ = *(const f16x8*)(wfp);                                               \
    A1_ = *(const f16x8*)(wfp + 512);                                         \
  }

  f32x4 acc[2][6];
#pragma unroll
  for (int ot = 0; ot < 2; ++ot)
#pragma unroll
    for (int bt = 0; bt < 6; ++bt) acc[ot][bt] = (f32x4)(0.f);

#define MF(a, bx, o_, b_) \
  acc[o_][b_] = __builtin_amdgcn_mfma_f32_16x16x32_f16(a, bx, acc[o_][b_], 0, 0, 0);

#define MFMA12(A0_, A1_, BUF)                                                 \
  {                                                                           \
    const char* bb = Bs + (BUF) * 6144 + rpx * 64 + rsw;                      \
    f16x8 b0 = *(const f16x8*)(bb);                                           \
    f16x8 b1 = *(const f16x8*)(bb + 1024);                                    \
    f16x8 b2 = *(const f16x8*)(bb + 2048);                                    \
    f16x8 b3 = *(const f16x8*)(bb + 3072);                                    \
    f16x8 b4 = *(const f16x8*)(bb + 4096);                                    \
    f16x8 b5 = *(const f16x8*)(bb + 5120);                                    \
    __builtin_amdgcn_s_setprio(1);                                            \
    MF(A0_, b0, 0, 0) MF(A1_, b0, 1, 0)                                       \
    MF(A0_, b1, 0, 1) MF(A1_, b1, 1, 1)                                       \
    MF(A0_, b2, 0, 2) MF(A1_, b2, 1, 2)                                       \
    MF(A0_, b3, 0, 3) MF(A1_, b3, 1, 3)                                       \
    MF(A0_, b4, 0, 4) MF(A1_, b4, 1, 4)                                       \
    MF(A0_, b5, 0, 5) MF(A1_, b5, 1, 5)                                       \
    __builtin_amdgcn_s_setprio(0);                                            \
  }

  // --- prologue ---
  ISSUE(0)
  COMBINE_WRITE(0)
  ISSUE(1)
  LOADA(aA0, aA1, 0)
  LOADA(aB0, aB1, 1)
  RAW_BARRIER()

  // --- sections 0..69 (35 x 2) ---
  for (int sp = 0; sp < 35; ++sp) {
    const int s0 = 2 * sp, s1 = 2 * sp + 1;
    MFMA12(aA0, aA1, 0)
    LOADA(aA0, aA1, s0 + 2)
    COMBINE_WRITE(1)
    ISSUE(s0 + 2)
    RAW_BARRIER()
    MFMA12(aB0, aB1, 1)
    LOADA(aB0, aB1, s1 + 2)
    COMBINE_WRITE(0)
    ISSUE(s1 + 2)
    RAW_BARRIER()
  }
  // section 70 (buf0): stage 71 into buf1
  MFMA12(aA0, aA1, 0)
  COMBINE_WRITE(1)
  RAW_BARRIER()
  // section 71 (buf1)
  MFMA12(aB0, aB1, 1)

  // --- epilogue: stores + GN partials (gr aliased onto dead ctab) ---
  float* grA = (float*)ctab;          // [16][64]
  float* grB = grA + 1024;
  const int colb = lane & 15, prow = (lane >> 4) * 4;
#pragma unroll
  for (int ot = 0; ot < 2; ++ot) {
    float s1 = 0.f, s2 = 0.f;
#pragma unroll
    for (int bt = 0; bt < 6; ++bt) {
      const int jj = bt * 16 + colb;
      const int row = ty * 8 + jj / 12, col = tx * 12 + jj % 12;
      const f32x4 a = acc[ot][bt];
      if (row < HH && col < WW) {
        float* op = out + ((size_t)(n * COUTC + wv * 32 + ot * 16 + prow)) * HW +
                    row * WW + col;
        op[0] = a[0];
        op[HW] = a[1];
        op[2 * HW] = a[2];
        op[3 * HW] = a[3];
      }
      s1 += a[0] + a[1] + a[2] + a[3];
      s2 += a[0] * a[0] + a[1] * a[1] + a[2] * a[2] + a[3] * a[3];
    }
    grA[(wv * 2 + ot) * 64 + lane] = s1;
    grB[(wv * 2 + ot) * 64 + lane] = s2;
  }
  __syncthreads();
  if (tid < 32) {
    const int wv2 = tid >> 2, ot2 = (tid >> 1) & 1, hb = tid & 1;
    float a1 = 0.f, a2 = 0.f;
#pragma unroll 8
    for (int l = 0; l < 32; ++l) {
      a1 += grA[(wv2 * 2 + ot2) * 64 + hb * 32 + l];
      a2 += grB[(wv2 * 2 + ot2) * 64 + hb * 32 + l];
    }
    float* pp = part + (((size_t)n * NT2 + rem) * GG + tid) * 2;
    pp[0] = a1;
    pp[1] = a2;
  }
}

// ---------------------------------------------------------------------------
// k4: GroupNorm affine + ReLU, stats fused. 4096 elems/block (grid 2500).
// ---------------------------------------------------------------------------
__global__ void __launch_bounds__(256) k4_norm(float* __restrict__ out,
                                               const float* __restrict__ part,
                                               const float* __restrict__ gw,
                                               const float* __restrict__ gb) {
  const int b = blockIdx.x;              // 2500
  const int tid = threadIdx.x;
  const size_t idx0 = (size_t)b * 4096;
  const int n = (int)(idx0 / ((size_t)COUTC * HW));
  const int r0 = (int)(idx0 % ((size_t)COUTC * HW));
  const int gfirst = (r0 / HW) >> 3;
  const int glast = ((r0 + 4095) / HW) >> 3;
  const int ngrp = (glast > gfirst) ? 2 : 1;

  __shared__ float rr[4][2];
  __shared__ float sm[2][2];

  for (int wgrp = 0; wgrp < ngrp; ++wgrp) {
    const int g = wgrp ? glast : gfirst;
    float s1 = 0.f, s2 = 0.f;
    if (tid < NT2) {
      const float* pp = part + (((size_t)n * NT2 + tid) * GG + g) * 2;
      s1 = pp[0];
      s2 = pp[1];
    }
#pragma unroll
    for (int off = 32; off > 0; off >>= 1) {
      s1 += __shfl_down(s1, off);
      s2 += __shfl_down(s2, off);
    }
    if ((tid & 63) == 0) { rr[tid >> 6][0] = s1; rr[tid >> 6][1] = s2; }
    __syncthreads();
    if (tid == 0) {
      const float a1 = rr[0][0] + rr[1][0] + rr[2][0] + rr[3][0];
      const float a2 = rr[0][1] + rr[1][1] + rr[2][1] + rr[3][1];
      const float cnt = 8.0f * (float)HW;
      const float mean = a1 / cnt;
      const float var = a2 / cnt - mean * mean;
      sm[wgrp][0] = mean;
      sm[wgrp][1] = rsqrtf(var + EPSF);
    }
    __syncthreads();
  }

#pragma unroll
  for (int p = 0; p < 4; ++p) {
    const size_t idx = idx0 + (size_t)p * 1024 + (size_t)tid * 4;
    const int o = (int)((idx % ((size_t)COUTC * HW)) / HW);
    const int g = o >> 3;
    const int which = (g == gfirst) ? 0 : 1;
    const float mean = sm[which][0];
    const float rs = sm[which][1];
    const float sc = rs * gw[o];
    const float sh = gb[o] - mean * sc;
    float4 v = *(float4*)(out + idx);
    v.x = fmaxf(fmaf(v.x, sc, sh), 0.f);
    v.y = fmaxf(fmaf(v.y, sc, sh), 0.f);
    v.z = fmaxf(fmaf(v.z, sc, sh), 0.f);
    v.w = fmaxf(fmaf(v.w, sc, sh), 0.f);
    *(float4*)(out + idx) = v;
  }
}

// ---------------------------------------------------------------------------
extern "C" void kernel_launch(void* const* d_in, const int* in_sizes, int n_in,
                              void* d_out, int out_size, void* d_ws, size_t ws_size,
                              hipStream_t stream) {
  const float* x    = (const float*)d_in[0];
  const float* w_tm = (const float*)d_in[1];
  const float* b_tm = (const float*)d_in[2];
  const float* w_tr = (const float*)d_in[3];
  const float* b_tr = (const float*)d_in[4];
  const float* w_def = (const float*)d_in[5];
  const float* gn_w = (const float*)d_in[6];
  const float* gn_b = (const float*)d_in[7];
  float* out = (float*)d_out;
  float* ws = (float*)d_ws;

  float* posy  = ws;                                     // 360000 f32
  float* posx  = ws + 360000;                            // 360000 f32
  _Float16* wfrag = (_Float16*)(ws + 720000);            // 589824 fp16
  _Float16* wf6   = (_Float16*)(ws + 1014912);           // 36864 fp16
  _Float16* xh    = (_Float16*)(ws + 1033344);           // 10.24M fp16
  float* part  = ws + 6153344;                           // 4*117*32*2 = 29952 f32

  hipLaunchKernelGGL(kt_prep, dim3(4960), dim3(256), 0, stream,
                     x, w_def, w_tm, w_tr, xh, wfrag, wf6);
  hipLaunchKernelGGL(k1_off, dim3(625), dim3(256), 0, stream,
                     xh, wf6, b_tm, b_tr, posy, posx);
  hipLaunchKernelGGL(k2_deform, dim3(NWG), dim3(512), 0, stream,
                     xh, wfrag, posy, posx, out, part);
  hipLaunchKernelGGL(k4_norm, dim3(2500), dim3(256), 0, stream,
                     out, part, gn_w, gn_b);
}